// Round 3
// baseline (347.259 us; speedup 1.0000x reference)
//
#include <hip/hip_runtime.h>
#include <hip/hip_bf16.h>

#define F 128
#define C_CLS 40
#define NWSPLIT 35
#define ELLCAP 32

typedef __attribute__((ext_vector_type(8))) short short8;
typedef __attribute__((ext_vector_type(4))) float float4v;
typedef unsigned short ushort;

__device__ inline float bf2f(ushort u) {
  unsigned int x = ((unsigned int)u) << 16;
  return __builtin_bit_cast(float, x);
}
__device__ inline ushort f2bf(float f) {
  __hip_bfloat16 h = __float2bfloat16(f);
  return __builtin_bit_cast(ushort, h);
}
__device__ inline void split_bf16(float f, ushort& hi, ushort& lo) {
  hi = f2bf(f);
  lo = f2bf(f - bf2f(hi));
}
__device__ inline int swz(int lane) { return lane ^ ((lane >> 4) & 3); }

// ---------------- setup (heterogeneous): weight-split | ELL fill ----------------
// Packed counters; ELL tails NOT zeroed here (prepass rewrites them to the zero row).
__global__ __launch_bounds__(256) void setup_kernel(
    const float* __restrict__ W1, const float* __restrict__ imp,
    const float* __restrict__ W2, const float* __restrict__ W3,
    const float* __restrict__ Wl1, const float* __restrict__ Wh2,
    ushort* __restrict__ WhP,
    ushort* __restrict__ W2hH, ushort* __restrict__ W2lH,
    const int* __restrict__ row, const int* __restrict__ col,
    int* __restrict__ cnt, int* __restrict__ ell,
    int ne, int n) {
  int b = blockIdx.x;
  if (b < NWSPLIT) {
    int ci = b * 256 + threadIdx.x;
    if (ci < 8192) {
      const float* src[4] = {W1, W2, W3, Wl1};
      int p = ci >> 11, c = ci & 2047;
      int kc = c >> 10, ct = (c >> 7) & 7, ks = (c >> 6) & 1, ln = c & 63;
      int dl = swz(ln);
      int colw = ct * 16 + (dl & 15);
      int k = kc * 64 + ks * 32 + (dl >> 4) * 8;
      float4 f0 = *(const float4*)&src[p][(size_t)colw * F + k];
      float4 f1 = *(const float4*)&src[p][(size_t)colw * F + k + 4];
      float v[8] = {f0.x, f0.y, f0.z, f0.w, f1.x, f1.y, f1.z, f1.w};
      if (p == 0) {
        float4 i0 = *(const float4*)&imp[k];
        float4 i1 = *(const float4*)&imp[k + 4];
        v[0] *= i0.x; v[1] *= i0.y; v[2] *= i0.z; v[3] *= i0.w;
        v[4] *= i1.x; v[5] *= i1.y; v[6] *= i1.z; v[7] *= i1.w;
      }
      ushort hi[8];
#pragma unroll
      for (int j = 0; j < 8; ++j) hi[j] = f2bf(v[j]);
      *(short8*)&WhP[(size_t)ci * 8] = *(short8*)hi;
    } else if (ci < 8192 + 768) {
      int c = ci - 8192;
      int ct = c >> 8, ks = (c >> 6) & 3, ln = c & 63;
      int colw = ct * 16 + (ln & 15);
      int k = ks * 32 + (ln >> 4) * 8;
      float v[8];
      if (colw < C_CLS) {
        float4 f0 = *(const float4*)&Wh2[(size_t)colw * F + k];
        float4 f1 = *(const float4*)&Wh2[(size_t)colw * F + k + 4];
        v[0] = f0.x; v[1] = f0.y; v[2] = f0.z; v[3] = f0.w;
        v[4] = f1.x; v[5] = f1.y; v[6] = f1.z; v[7] = f1.w;
      } else {
#pragma unroll
        for (int j = 0; j < 8; ++j) v[j] = 0.f;
      }
      ushort hi[8], lo[8];
#pragma unroll
      for (int j = 0; j < 8; ++j) split_bf16(v[j], hi[j], lo[j]);
      *(short8*)&W2hH[(size_t)c * 8] = *(short8*)hi;
      *(short8*)&W2lH[(size_t)c * 8] = *(short8*)lo;
    }
  } else {
    int e = (b - NWSPLIT) * 256 + threadIdx.x;
    if (e < ne) {
      int r = row[e], c = col[e];
      int p = atomicAdd(&cnt[c], 1);
      if (p < ELLCAP) ell[(size_t)c * ELLCAP + p] = r;
    }
  }
}

// ---------------- prepass (heterogeneous): wsum + ELL tail rewrite | x -> Xs | zero rows ----
// wsum[c] = dinv[c]*sum_r dinv[r] + 1/deg[c]  (layer-independent bias coefficient).
// Tail slots [cnt, roundup4(cnt)) -> n (the zero row), so conv loops need no gating.
// Xs = dinv[node] * x (bf16). Row n of both ping-pong buffers zeroed.
__global__ __launch_bounds__(256) void prepass_kernel(
    const float* __restrict__ x, const int* __restrict__ cnt,
    int* __restrict__ ell, float* __restrict__ wsum,
    ushort* __restrict__ Xs, ushort* __restrict__ Az,
    int n, int nbW, int nbX) {
  int b = blockIdx.x;
  if (b < nbW) {
    int node = b * 256 + threadIdx.x;
    if (node >= n) return;
    int cv = cnt[node];
    int lim = cv < ELLCAP ? cv : ELLCAP;
    int lim4 = (lim + 3) & ~3;
    float gs = 0.f;
    const int4* ep = (const int4*)&ell[(size_t)node * ELLCAP];
    for (int base = 0; base < lim; base += 4) {
      int4 rr = ep[base >> 2];
      bool p1 = base + 1 < lim, p2 = base + 2 < lim, p3 = base + 3 < lim;
      int r1 = p1 ? rr.y : rr.x;
      int r2 = p2 ? rr.z : rr.x;
      int r3 = p3 ? rr.w : rr.x;
      float g0 = rsqrtf((float)(cnt[rr.x] + 1));
      float g1 = p1 ? rsqrtf((float)(cnt[r1] + 1)) : 0.f;
      float g2 = p2 ? rsqrtf((float)(cnt[r2] + 1)) : 0.f;
      float g3 = p3 ? rsqrtf((float)(cnt[r3] + 1)) : 0.f;
      gs += (g0 + g1) + (g2 + g3);
    }
    float d = (float)(cv + 1);
    wsum[node] = rsqrtf(d) * gs + 1.0f / d;
    for (int p = lim; p < lim4; ++p) ell[(size_t)node * ELLCAP + p] = n;
  } else if (b < nbW + nbX) {
    size_t i = (size_t)(b - nbW) * 2048 + (size_t)threadIdx.x * 8;
    if (i < (size_t)n * F) {
      int node = (int)(i >> 7);
      float dc = rsqrtf((float)(cnt[node] + 1));
      float4 f0 = *(const float4*)&x[i];
      float4 f1 = *(const float4*)&x[i + 4];
      ushort o[8] = {f2bf(dc * f0.x), f2bf(dc * f0.y), f2bf(dc * f0.z), f2bf(dc * f0.w),
                     f2bf(dc * f1.x), f2bf(dc * f1.y), f2bf(dc * f1.z), f2bf(dc * f1.w)};
      *(short8*)&Xs[i] = *(short8*)o;
    }
  } else {
    int t = threadIdx.x;
    short8 z = (short8){0, 0, 0, 0, 0, 0, 0, 0};
    if (t < 16) *(short8*)&Xs[(size_t)n * F + t * 8] = z;
    else if (t < 32) *(short8*)&Az[(size_t)n * F + (t - 16) * 8] = z;
  }
}

// ---------------- fused conv: pure-sum gather + MFMA (weights direct from L2) ----------------
// S = dc*(sum_nbr Xs[r] + Xs[node]); out = relu((S@W^T + wsum*bl)*invdeg + bc), optionally
// pre-scaled by dc for the next layer's gather. No LDS, no barriers: waves independent,
// occupancy capped only by VGPR. One wave = 16 nodes (node<->lane&15, chunk<->quad).
template <bool SCALE_OUT>
__global__ __launch_bounds__(256) void conv_fused(
    const int* __restrict__ cnt, const int* __restrict__ ell,
    const ushort* __restrict__ Xs, const ushort* __restrict__ Wh,
    const float* __restrict__ wsum, const float* __restrict__ bl,
    const float* __restrict__ bc, ushort* __restrict__ OUT, int n) {
  const int t = threadIdx.x;
  const int w = t >> 6, lane = t & 63, quad = lane >> 4, cl = lane & 15;
  const int node = blockIdx.x * 64 + w * 16 + cl;

  float acc[4][8];
#pragma unroll
  for (int ks = 0; ks < 4; ++ks)
#pragma unroll
    for (int q = 0; q < 8; ++q) acc[ks][q] = 0.f;

  float dc = 1.f, id = 1.f;
  int lim4 = 0;
  if (node < n) {
    int cv = cnt[node];
    float d = (float)(cv + 1);
    dc = rsqrtf(d);
    id = 1.0f / d;
    int lim = cv < ELLCAP ? cv : ELLCAP;
    lim4 = (lim + 3) & ~3;
  }
  const int4* ep = (const int4*)&ell[(size_t)node * ELLCAP];
  const int qoff = quad * 8;

  for (int base = 0; base < lim4; base += 4) {
    int4 rr = ep[base >> 2];
    const ushort* q0 = &Xs[(size_t)rr.x * F + qoff];
    const ushort* q1 = &Xs[(size_t)rr.y * F + qoff];
    const ushort* q2 = &Xs[(size_t)rr.z * F + qoff];
    const ushort* q3 = &Xs[(size_t)rr.w * F + qoff];
#pragma unroll
    for (int ks = 0; ks < 4; ++ks) {
      short8 v0 = *(const short8*)&q0[ks * 32];
      short8 v1 = *(const short8*)&q1[ks * 32];
      short8 v2 = *(const short8*)&q2[ks * 32];
      short8 v3 = *(const short8*)&q3[ks * 32];
#pragma unroll
      for (int q = 0; q < 8; ++q) {
        float t0 = bf2f((ushort)v0[q]) + bf2f((ushort)v1[q]);
        float t1 = bf2f((ushort)v2[q]) + bf2f((ushort)v3[q]);
        acc[ks][q] += t0 + t1;
      }
    }
  }

  // self-loop + finalize S as bf16 B-fragments
  short8 sfrag[4];
  if (node < n) {
    const ushort* sq = &Xs[(size_t)node * F + qoff];
#pragma unroll
    for (int ks = 0; ks < 4; ++ks) {
      short8 sv = *(const short8*)&sq[ks * 32];
      ushort o[8];
#pragma unroll
      for (int q = 0; q < 8; ++q)
        o[q] = f2bf(dc * (acc[ks][q] + bf2f((ushort)sv[q])));
      sfrag[ks] = *(short8*)o;
    }
  } else {
#pragma unroll
    for (int ks = 0; ks < 4; ++ks) sfrag[ks] = (short8){0, 0, 0, 0, 0, 0, 0, 0};
  }

  float4v co[8];
#pragma unroll
  for (int mt = 0; mt < 8; ++mt) co[mt] = (float4v){0.f, 0.f, 0.f, 0.f};
  const int sl = swz(lane);
#pragma unroll
  for (int ks = 0; ks < 4; ++ks) {
    const int base2 = ((ks >> 1) * 1024 + (ks & 1) * 64 + sl) * 8;
#pragma unroll
    for (int mt = 0; mt < 8; ++mt) {
      short8 a_h = *(const short8*)&Wh[base2 + mt * 1024];
      co[mt] = __builtin_amdgcn_mfma_f32_16x16x32_bf16(a_h, sfrag[ks], co[mt], 0, 0, 0);
    }
  }

  if (node < n) {
    float ws = wsum[node];
#pragma unroll
    for (int mt = 0; mt < 8; ++mt) {
      float4 blv = *(const float4*)&bl[mt * 16 + quad * 4];
      float4 bcv = *(const float4*)&bc[mt * 16 + quad * 4];
      float v0 = fmaxf((co[mt][0] + ws * blv.x) * id + bcv.x, 0.f);
      float v1 = fmaxf((co[mt][1] + ws * blv.y) * id + bcv.y, 0.f);
      float v2 = fmaxf((co[mt][2] + ws * blv.z) * id + bcv.z, 0.f);
      float v3 = fmaxf((co[mt][3] + ws * blv.w) * id + bcv.w, 0.f);
      if (SCALE_OUT) { v0 *= dc; v1 *= dc; v2 *= dc; v3 *= dc; }
      ushort o[4] = {f2bf(v0), f2bf(v1), f2bf(v2), f2bf(v3)};
      *(ushort4*)&OUT[(size_t)node * F + mt * 16 + quad * 4] = *(ushort4*)o;
    }
  }
}

// ---------------- fused head: h = relu(X@Wl1^T+b) in LDS, then logits + log_softmax ----
// Weights read direct from L2 (no staging); only the 16 KB per-wave h-tile uses LDS.
__global__ __launch_bounds__(256) void head_fused(const ushort* __restrict__ X,
    const ushort* __restrict__ Wl1h, const float* __restrict__ bl,
    const ushort* __restrict__ W2h, const ushort* __restrict__ W2l,
    const float* __restrict__ b2, float* __restrict__ out, int nrows) {
  __shared__ ushort sH[8192];            // 16 KB h-tile (4 waves x 16 x 128 bf16)
  __shared__ float b2s[48];
  const int t = threadIdx.x;
  if (t < 48) b2s[t] = (t < C_CLS) ? b2[t] : -1e30f;

  const int w = t >> 6, lane = t & 63;
  const int quad = lane >> 4, cl = lane & 15;
  const int sl = swz(lane);
  const int row0 = (blockIdx.x * 4 + w) * 16;
  char* sHb = (char*)sH;

  // ---- phase 1: h[cl][0..127] for this wave's 16 rows ----
  float4v acc1[8];
#pragma unroll
  for (int mt = 0; mt < 8; ++mt) acc1[mt] = (float4v){0.f, 0.f, 0.f, 0.f};
  const int gr1 = row0 + cl;
#pragma unroll
  for (int ks = 0; ks < 4; ++ks) {
    short8 b;
    if (gr1 < nrows) b = *(const short8*)&X[(size_t)gr1 * F + ks * 32 + quad * 8];
    else b = (short8){0, 0, 0, 0, 0, 0, 0, 0};
    const int base = ((ks >> 1) * 1024 + (ks & 1) * 64 + sl) * 8;
#pragma unroll
    for (int mt = 0; mt < 8; ++mt) {
      short8 a_h = *(const short8*)&Wl1h[base + mt * 1024];
      acc1[mt] = __builtin_amdgcn_mfma_f32_16x16x32_bf16(a_h, b, acc1[mt], 0, 0, 0);
    }
  }
#pragma unroll
  for (int mt = 0; mt < 8; ++mt) {
    float4 bv = *(const float4*)&bl[mt * 16 + quad * 4];
    ushort o[4];
    o[0] = f2bf(fmaxf(acc1[mt][0] + bv.x, 0.f));
    o[1] = f2bf(fmaxf(acc1[mt][1] + bv.y, 0.f));
    o[2] = f2bf(fmaxf(acc1[mt][2] + bv.z, 0.f));
    o[3] = f2bf(fmaxf(acc1[mt][3] + bv.w, 0.f));
    int ch = (mt * 2 + (quad >> 1)) ^ cl;
    *(ushort4*)&sHb[w * 4096 + cl * 256 + ch * 16 + (quad & 1) * 8] = *(ushort4*)o;
  }
  __syncthreads();

  // ---- phase 2: logits = h @ W2^T (hi+lo), fused log_softmax ----
  float4v acc[3];
#pragma unroll
  for (int ct = 0; ct < 3; ++ct) acc[ct] = (float4v){0.f, 0.f, 0.f, 0.f};
#pragma unroll
  for (int ks = 0; ks < 4; ++ks) {
    int ch2 = (ks * 4 + quad) ^ cl;
    short8 a = *(short8*)&sHb[w * 4096 + cl * 256 + ch2 * 16];
#pragma unroll
    for (int ct = 0; ct < 3; ++ct) {
      int chunk = ((ct * 4 + ks) * 64 + lane) * 8;
      short8 b_h = *(const short8*)&W2h[chunk];
      short8 b_l = *(const short8*)&W2l[chunk];
      acc[ct] = __builtin_amdgcn_mfma_f32_16x16x32_bf16(a, b_h, acc[ct], 0, 0, 0);
      acc[ct] = __builtin_amdgcn_mfma_f32_16x16x32_bf16(a, b_l, acc[ct], 0, 0, 0);
    }
  }

  float b0 = b2s[cl], b1 = b2s[16 + cl], b2v = b2s[32 + cl];
  float lse[4];
#pragma unroll
  for (int reg = 0; reg < 4; ++reg) {
    float v0 = acc[0][reg] + b0;
    float v1 = acc[1][reg] + b1;
    float v2 = acc[2][reg] + b2v;
    acc[0][reg] = v0; acc[1][reg] = v1; acc[2][reg] = v2;
    float m = fmaxf(fmaxf(v0, v1), v2);
#pragma unroll
    for (int o = 1; o < 16; o <<= 1) m = fmaxf(m, __shfl_xor(m, o));
    float s = __expf(v0 - m) + __expf(v1 - m) + __expf(v2 - m);
#pragma unroll
    for (int o = 1; o < 16; o <<= 1) s += __shfl_xor(s, o);
    lse[reg] = logf(s) + m;
  }
#pragma unroll
  for (int reg = 0; reg < 4; ++reg) {
    int gr = row0 + quad * 4 + reg;
    if (gr < nrows) {
      out[(size_t)gr * C_CLS + cl] = acc[0][reg] - lse[reg];
      out[(size_t)gr * C_CLS + 16 + cl] = acc[1][reg] - lse[reg];
      if (cl < 8) out[(size_t)gr * C_CLS + 32 + cl] = acc[2][reg] - lse[reg];
    }
  }
}

extern "C" void kernel_launch(void* const* d_in, const int* in_sizes, int n_in,
                              void* d_out, int out_size, void* d_ws, size_t ws_size,
                              hipStream_t stream) {
  const float* x    = (const float*)d_in[0];
  const int*   ei   = (const int*)d_in[1];
  const float* imp  = (const float*)d_in[2];
  const float* W1   = (const float*)d_in[3];
  const float* bl1  = (const float*)d_in[4];
  const float* bc1  = (const float*)d_in[5];
  const float* W2   = (const float*)d_in[6];
  const float* bl2  = (const float*)d_in[7];
  const float* bc2  = (const float*)d_in[8];
  const float* W3   = (const float*)d_in[9];
  const float* bl3  = (const float*)d_in[10];
  const float* bc3  = (const float*)d_in[11];
  const float* Wl1  = (const float*)d_in[12];
  const float* bli1 = (const float*)d_in[13];
  const float* Wl2  = (const float*)d_in[14];
  const float* bli2 = (const float*)d_in[15];
  float* out = (float*)d_out;

  const int N = in_sizes[0] / F;      // 100000
  const int E = in_sizes[1] / 2;      // 600000

  // ping-pong buffers have N+1 rows; row N is the shared zero row for ELL tails
  ushort* A16 = (ushort*)d_ws;                     // (N+1)*F
  ushort* B16 = A16 + (size_t)(N + 1) * F;         // (N+1)*F
  ushort* WhP = B16 + (size_t)(N + 1) * F;         // 8192*8
  ushort* W2hH = WhP + 65536;                      // 768*8
  ushort* W2lH = W2hH + 6144;                      // 768*8
  float* wsum = (float*)(W2lH + 6144);             // N
  int*   cnt  = (int*)(wsum + N);                  // N (packed)
  int*   ell  = cnt + N;                           // 32N

  const int* rowv = ei;
  const int* colv = ei + E;

  int nbE  = (E + 255) / 256;
  int nbW  = (N + 255) / 256;          // prepass wsum blocks
  int nbX  = (N * F + 2047) / 2048;    // prepass x->Xs blocks (8 elems/thread)
  int nbCv = (N + 63) / 64;            // conv blocks (64 nodes each)
  int nbHd = (N + 63) / 64;

  // ---- one-time prep ----
  hipMemsetAsync(cnt, 0, (size_t)N * sizeof(int), stream);
  setup_kernel<<<NWSPLIT + nbE, 256, 0, stream>>>(
      W1, imp, W2, W3, Wl1, Wl2, WhP, W2hH, W2lH, rowv, colv, cnt, ell, E, N);
  prepass_kernel<<<nbW + nbX + 1, 256, 0, stream>>>(
      x, cnt, ell, wsum, B16, A16, N, nbW, nbX);

  // ---- conv layers: pure-sum gather + fused GEMM (imp folded into WhP layer 1) ----
  conv_fused<true ><<<nbCv, 256, 0, stream>>>(cnt, ell, B16, WhP,         wsum, bl1, bc1, A16, N);
  conv_fused<true ><<<nbCv, 256, 0, stream>>>(cnt, ell, A16, WhP + 16384, wsum, bl2, bc2, B16, N);
  conv_fused<false><<<nbCv, 256, 0, stream>>>(cnt, ell, B16, WhP + 32768, wsum, bl3, bc3, A16, N);

  // ---- fused dense head + log_softmax ----
  head_fused<<<nbHd, 256, 0, stream>>>(A16, WhP + 49152, bli1, W2hH, W2lH, bli2, out, N);
}

// Round 4
// 335.706 us; speedup vs baseline: 1.0344x; 1.0344x over previous
//
#include <hip/hip_runtime.h>
#include <hip/hip_bf16.h>

#define F 128
#define C_CLS 40
#define NWSPLIT 35
#define ELLCAP 32
#define NBKT 9

typedef __attribute__((ext_vector_type(8))) short short8;
typedef __attribute__((ext_vector_type(4))) float float4v;
typedef unsigned short ushort;

__device__ inline float bf2f(ushort u) {
  unsigned int x = ((unsigned int)u) << 16;
  return __builtin_bit_cast(float, x);
}
__device__ inline ushort f2bf(float f) {
  __hip_bfloat16 h = __float2bfloat16(f);
  return __builtin_bit_cast(ushort, h);
}
__device__ inline void split_bf16(float f, ushort& hi, ushort& lo) {
  hi = f2bf(f);
  lo = f2bf(f - bf2f(hi));
}
__device__ inline int swz(int lane) { return lane ^ ((lane >> 4) & 3); }
// bucket: descending by iteration count (long waves launch first)
__device__ inline int bucket_of(int cv) {
  int lim = cv < ELLCAP ? cv : ELLCAP;
  int nIt = (lim + 3) >> 2;           // 0..8
  return 8 - nIt;                     // 0 = deg 29..32
}

// ---------------- setup (heterogeneous): weight-split | ELL fill ----------------
__global__ __launch_bounds__(256) void setup_kernel(
    const float* __restrict__ W1, const float* __restrict__ imp,
    const float* __restrict__ W2, const float* __restrict__ W3,
    const float* __restrict__ Wl1, const float* __restrict__ Wh2,
    ushort* __restrict__ WhP,
    ushort* __restrict__ W2hH, ushort* __restrict__ W2lH,
    const int* __restrict__ row, const int* __restrict__ col,
    int* __restrict__ cnt, int* __restrict__ ell,
    int ne, int n) {
  int b = blockIdx.x;
  if (b < NWSPLIT) {
    int ci = b * 256 + threadIdx.x;
    if (ci < 8192) {
      const float* src[4] = {W1, W2, W3, Wl1};
      int p = ci >> 11, c = ci & 2047;
      int kc = c >> 10, ct = (c >> 7) & 7, ks = (c >> 6) & 1, ln = c & 63;
      int dl = swz(ln);
      int colw = ct * 16 + (dl & 15);
      int k = kc * 64 + ks * 32 + (dl >> 4) * 8;
      float4 f0 = *(const float4*)&src[p][(size_t)colw * F + k];
      float4 f1 = *(const float4*)&src[p][(size_t)colw * F + k + 4];
      float v[8] = {f0.x, f0.y, f0.z, f0.w, f1.x, f1.y, f1.z, f1.w};
      if (p == 0) {
        float4 i0 = *(const float4*)&imp[k];
        float4 i1 = *(const float4*)&imp[k + 4];
        v[0] *= i0.x; v[1] *= i0.y; v[2] *= i0.z; v[3] *= i0.w;
        v[4] *= i1.x; v[5] *= i1.y; v[6] *= i1.z; v[7] *= i1.w;
      }
      ushort hi[8];
#pragma unroll
      for (int j = 0; j < 8; ++j) hi[j] = f2bf(v[j]);
      *(short8*)&WhP[(size_t)ci * 8] = *(short8*)hi;
    } else if (ci < 8192 + 768) {
      int c = ci - 8192;
      int ct = c >> 8, ks = (c >> 6) & 3, ln = c & 63;
      int colw = ct * 16 + (ln & 15);
      int k = ks * 32 + (ln >> 4) * 8;
      float v[8];
      if (colw < C_CLS) {
        float4 f0 = *(const float4*)&Wh2[(size_t)colw * F + k];
        float4 f1 = *(const float4*)&Wh2[(size_t)colw * F + k + 4];
        v[0] = f0.x; v[1] = f0.y; v[2] = f0.z; v[3] = f0.w;
        v[4] = f1.x; v[5] = f1.y; v[6] = f1.z; v[7] = f1.w;
      } else {
#pragma unroll
        for (int j = 0; j < 8; ++j) v[j] = 0.f;
      }
      ushort hi[8], lo[8];
#pragma unroll
      for (int j = 0; j < 8; ++j) split_bf16(v[j], hi[j], lo[j]);
      *(short8*)&W2hH[(size_t)c * 8] = *(short8*)hi;
      *(short8*)&W2lH[(size_t)c * 8] = *(short8*)lo;
    }
  } else {
    int e = (b - NWSPLIT) * 256 + threadIdx.x;
    if (e < ne) {
      int r = row[e], c = col[e];
      int p = atomicAdd(&cnt[c], 1);
      if (p < ELLCAP) ell[(size_t)c * ELLCAP + p] = r;
    }
  }
}

// ---------------- prepass1: wsum + ELL tail rewrite + bucket hist | x -> Xs | zero rows ----
__global__ __launch_bounds__(256) void prepass_kernel(
    const float* __restrict__ x, const int* __restrict__ cnt,
    int* __restrict__ ell, float* __restrict__ wsum, int* __restrict__ hist,
    ushort* __restrict__ Xs, ushort* __restrict__ Az,
    int n, int nbW, int nbX) {
  int b = blockIdx.x;
  if (b < nbW) {
    __shared__ int lh[NBKT];
    int t = threadIdx.x;
    if (t < NBKT) lh[t] = 0;
    __syncthreads();
    int node = b * 256 + t;
    if (node < n) {
      int cv = cnt[node];
      int lim = cv < ELLCAP ? cv : ELLCAP;
      int lim4 = (lim + 3) & ~3;
      float gs = 0.f;
      const int4* ep = (const int4*)&ell[(size_t)node * ELLCAP];
      for (int base = 0; base < lim; base += 4) {
        int4 rr = ep[base >> 2];
        bool p1 = base + 1 < lim, p2 = base + 2 < lim, p3 = base + 3 < lim;
        int r1 = p1 ? rr.y : rr.x;
        int r2 = p2 ? rr.z : rr.x;
        int r3 = p3 ? rr.w : rr.x;
        float g0 = rsqrtf((float)(cnt[rr.x] + 1));
        float g1 = p1 ? rsqrtf((float)(cnt[r1] + 1)) : 0.f;
        float g2 = p2 ? rsqrtf((float)(cnt[r2] + 1)) : 0.f;
        float g3 = p3 ? rsqrtf((float)(cnt[r3] + 1)) : 0.f;
        gs += (g0 + g1) + (g2 + g3);
      }
      float d = (float)(cv + 1);
      wsum[node] = rsqrtf(d) * gs + 1.0f / d;
      for (int p = lim; p < lim4; ++p) ell[(size_t)node * ELLCAP + p] = n;
      atomicAdd(&lh[bucket_of(cv)], 1);
    }
    __syncthreads();
    if (t < NBKT) atomicAdd(&hist[t], lh[t]);
  } else if (b < nbW + nbX) {
    size_t i = (size_t)(b - nbW) * 2048 + (size_t)threadIdx.x * 8;
    if (i < (size_t)n * F) {
      int node = (int)(i >> 7);
      float dc = rsqrtf((float)(cnt[node] + 1));
      float4 f0 = *(const float4*)&x[i];
      float4 f1 = *(const float4*)&x[i + 4];
      ushort o[8] = {f2bf(dc * f0.x), f2bf(dc * f0.y), f2bf(dc * f0.z), f2bf(dc * f0.w),
                     f2bf(dc * f1.x), f2bf(dc * f1.y), f2bf(dc * f1.z), f2bf(dc * f1.w)};
      *(short8*)&Xs[i] = *(short8*)o;
    }
  } else {
    int t = threadIdx.x;
    short8 z = (short8){0, 0, 0, 0, 0, 0, 0, 0};
    if (t < 16) *(short8*)&Xs[(size_t)n * F + t * 8] = z;
    else if (t < 32) *(short8*)&Az[(size_t)n * F + (t - 16) * 8] = z;
  }
}

// ---------------- prepass2: degree-bucket counting-sort scatter -> perm ----------------
// Each block: LDS-local bucket counts, then per-bucket base = prefix(hist) + cursor
// reservation (one global atomic per bucket per block).
__global__ __launch_bounds__(256) void perm_kernel(
    const int* __restrict__ cnt, const int* __restrict__ hist,
    int* __restrict__ cursor, int* __restrict__ perm, int n) {
  __shared__ int lh[NBKT], lbase[NBKT];
  int t = threadIdx.x;
  if (t < NBKT) lh[t] = 0;
  __syncthreads();
  int node = blockIdx.x * 256 + t;
  int bkt = 0, idx = 0;
  if (node < n) {
    bkt = bucket_of(cnt[node]);
    idx = atomicAdd(&lh[bkt], 1);
  }
  __syncthreads();
  if (t < NBKT) {
    int pre = 0;
#pragma unroll
    for (int k = 0; k < NBKT; ++k)
      if (k < t) pre += hist[k];
    lbase[t] = pre + atomicAdd(&cursor[t], lh[t]);
  }
  __syncthreads();
  if (node < n) perm[lbase[bkt] + idx] = node;
}

// ---------------- fused conv: degree-uniform waves, prefetched ELL, MFMA from L2 ----------------
// S = dc*(sum_nbr Xs[r] + Xs[node]); out = relu((S@W^T + wsum*bl)*invdeg + bc)[*dc].
// node = perm[gid]: all 16 nodes of a wave share ~one degree bucket -> no divergence
// inflation, no straggler drain. Next ep int4 prefetched before row consumption.
template <bool SCALE_OUT>
__global__ __launch_bounds__(256) void conv_fused(
    const int* __restrict__ cnt, const int* __restrict__ ell,
    const int* __restrict__ perm,
    const ushort* __restrict__ Xs, const ushort* __restrict__ Wh,
    const float* __restrict__ wsum, const float* __restrict__ bl,
    const float* __restrict__ bc, ushort* __restrict__ OUT, int n) {
  const int t = threadIdx.x;
  const int w = t >> 6, lane = t & 63, quad = lane >> 4, cl = lane & 15;
  const int gid = blockIdx.x * 64 + w * 16 + cl;
  const bool valid = gid < n;
  const int node = valid ? perm[gid] : 0;

  float acc[4][8];
#pragma unroll
  for (int ks = 0; ks < 4; ++ks)
#pragma unroll
    for (int q = 0; q < 8; ++q) acc[ks][q] = 0.f;

  float dc = 1.f, id = 1.f;
  int nIt = 0;
  if (valid) {
    int cv = cnt[node];
    float d = (float)(cv + 1);
    dc = rsqrtf(d);
    id = 1.0f / d;
    int lim = cv < ELLCAP ? cv : ELLCAP;
    nIt = (lim + 3) >> 2;
  }
  const int4* ep = (const int4*)&ell[(size_t)node * ELLCAP];
  const int qoff = quad * 8;

  if (nIt > 0) {
    int4 rr = ep[0];
    for (int it = 0; it < nIt; ++it) {
      const ushort* r0 = &Xs[(size_t)rr.x * F + qoff];
      const ushort* r1 = &Xs[(size_t)rr.y * F + qoff];
      const ushort* r2 = &Xs[(size_t)rr.z * F + qoff];
      const ushort* r3 = &Xs[(size_t)rr.w * F + qoff];
      short8 v[4][4];
#pragma unroll
      for (int ks = 0; ks < 4; ++ks) {
        v[0][ks] = *(const short8*)&r0[ks * 32];
        v[1][ks] = *(const short8*)&r1[ks * 32];
        v[2][ks] = *(const short8*)&r2[ks * 32];
        v[3][ks] = *(const short8*)&r3[ks * 32];
      }
      int jn = (it + 1 < nIt) ? it + 1 : it;
      rr = ep[jn];  // prefetch next indices while rows are in flight
#pragma unroll
      for (int ks = 0; ks < 4; ++ks)
#pragma unroll
        for (int q = 0; q < 8; ++q) {
          float t0 = bf2f((ushort)v[0][ks][q]) + bf2f((ushort)v[1][ks][q]);
          float t1 = bf2f((ushort)v[2][ks][q]) + bf2f((ushort)v[3][ks][q]);
          acc[ks][q] += t0 + t1;
        }
    }
  }

  // self-loop + finalize S as bf16 B-fragments
  short8 sfrag[4];
  if (valid) {
    const ushort* sq = &Xs[(size_t)node * F + qoff];
#pragma unroll
    for (int ks = 0; ks < 4; ++ks) {
      short8 sv = *(const short8*)&sq[ks * 32];
      ushort o[8];
#pragma unroll
      for (int q = 0; q < 8; ++q)
        o[q] = f2bf(dc * (acc[ks][q] + bf2f((ushort)sv[q])));
      sfrag[ks] = *(short8*)o;
    }
  } else {
#pragma unroll
    for (int ks = 0; ks < 4; ++ks) sfrag[ks] = (short8){0, 0, 0, 0, 0, 0, 0, 0};
  }

  float4v co[8];
#pragma unroll
  for (int mt = 0; mt < 8; ++mt) co[mt] = (float4v){0.f, 0.f, 0.f, 0.f};
  const int sl = swz(lane);
#pragma unroll
  for (int ks = 0; ks < 4; ++ks) {
    const int base2 = ((ks >> 1) * 1024 + (ks & 1) * 64 + sl) * 8;
#pragma unroll
    for (int mt = 0; mt < 8; ++mt) {
      short8 a_h = *(const short8*)&Wh[base2 + mt * 1024];
      co[mt] = __builtin_amdgcn_mfma_f32_16x16x32_bf16(a_h, sfrag[ks], co[mt], 0, 0, 0);
    }
  }

  if (valid) {
    float ws = wsum[node];
#pragma unroll
    for (int mt = 0; mt < 8; ++mt) {
      float4 blv = *(const float4*)&bl[mt * 16 + quad * 4];
      float4 bcv = *(const float4*)&bc[mt * 16 + quad * 4];
      float v0 = fmaxf((co[mt][0] + ws * blv.x) * id + bcv.x, 0.f);
      float v1 = fmaxf((co[mt][1] + ws * blv.y) * id + bcv.y, 0.f);
      float v2 = fmaxf((co[mt][2] + ws * blv.z) * id + bcv.z, 0.f);
      float v3 = fmaxf((co[mt][3] + ws * blv.w) * id + bcv.w, 0.f);
      if (SCALE_OUT) { v0 *= dc; v1 *= dc; v2 *= dc; v3 *= dc; }
      ushort o[4] = {f2bf(v0), f2bf(v1), f2bf(v2), f2bf(v3)};
      *(ushort4*)&OUT[(size_t)node * F + mt * 16 + quad * 4] = *(ushort4*)o;
    }
  }
}

// ---------------- fused head: h = relu(X@Wl1^T+b) in LDS, then logits + log_softmax ----
__global__ __launch_bounds__(256) void head_fused(const ushort* __restrict__ X,
    const ushort* __restrict__ Wl1h, const float* __restrict__ bl,
    const ushort* __restrict__ W2h, const ushort* __restrict__ W2l,
    const float* __restrict__ b2, float* __restrict__ out, int nrows) {
  __shared__ ushort sH[8192];            // 16 KB h-tile (4 waves x 16 x 128 bf16)
  __shared__ float b2s[48];
  const int t = threadIdx.x;
  if (t < 48) b2s[t] = (t < C_CLS) ? b2[t] : -1e30f;

  const int w = t >> 6, lane = t & 63;
  const int quad = lane >> 4, cl = lane & 15;
  const int sl = swz(lane);
  const int row0 = (blockIdx.x * 4 + w) * 16;
  char* sHb = (char*)sH;

  // ---- phase 1: h[cl][0..127] for this wave's 16 rows ----
  float4v acc1[8];
#pragma unroll
  for (int mt = 0; mt < 8; ++mt) acc1[mt] = (float4v){0.f, 0.f, 0.f, 0.f};
  const int gr1 = row0 + cl;
#pragma unroll
  for (int ks = 0; ks < 4; ++ks) {
    short8 b;
    if (gr1 < nrows) b = *(const short8*)&X[(size_t)gr1 * F + ks * 32 + quad * 8];
    else b = (short8){0, 0, 0, 0, 0, 0, 0, 0};
    const int base = ((ks >> 1) * 1024 + (ks & 1) * 64 + sl) * 8;
#pragma unroll
    for (int mt = 0; mt < 8; ++mt) {
      short8 a_h = *(const short8*)&Wl1h[base + mt * 1024];
      acc1[mt] = __builtin_amdgcn_mfma_f32_16x16x32_bf16(a_h, b, acc1[mt], 0, 0, 0);
    }
  }
#pragma unroll
  for (int mt = 0; mt < 8; ++mt) {
    float4 bv = *(const float4*)&bl[mt * 16 + quad * 4];
    ushort o[4];
    o[0] = f2bf(fmaxf(acc1[mt][0] + bv.x, 0.f));
    o[1] = f2bf(fmaxf(acc1[mt][1] + bv.y, 0.f));
    o[2] = f2bf(fmaxf(acc1[mt][2] + bv.z, 0.f));
    o[3] = f2bf(fmaxf(acc1[mt][3] + bv.w, 0.f));
    int ch = (mt * 2 + (quad >> 1)) ^ cl;
    *(ushort4*)&sHb[w * 4096 + cl * 256 + ch * 16 + (quad & 1) * 8] = *(ushort4*)o;
  }
  __syncthreads();

  // ---- phase 2: logits = h @ W2^T (hi+lo), fused log_softmax ----
  float4v acc[3];
#pragma unroll
  for (int ct = 0; ct < 3; ++ct) acc[ct] = (float4v){0.f, 0.f, 0.f, 0.f};
#pragma unroll
  for (int ks = 0; ks < 4; ++ks) {
    int ch2 = (ks * 4 + quad) ^ cl;
    short8 a = *(short8*)&sHb[w * 4096 + cl * 256 + ch2 * 16];
#pragma unroll
    for (int ct = 0; ct < 3; ++ct) {
      int chunk = ((ct * 4 + ks) * 64 + lane) * 8;
      short8 b_h = *(const short8*)&W2h[chunk];
      short8 b_l = *(const short8*)&W2l[chunk];
      acc[ct] = __builtin_amdgcn_mfma_f32_16x16x32_bf16(a, b_h, acc[ct], 0, 0, 0);
      acc[ct] = __builtin_amdgcn_mfma_f32_16x16x32_bf16(a, b_l, acc[ct], 0, 0, 0);
    }
  }

  float b0 = b2s[cl], b1 = b2s[16 + cl], b2v = b2s[32 + cl];
  float lse[4];
#pragma unroll
  for (int reg = 0; reg < 4; ++reg) {
    float v0 = acc[0][reg] + b0;
    float v1 = acc[1][reg] + b1;
    float v2 = acc[2][reg] + b2v;
    acc[0][reg] = v0; acc[1][reg] = v1; acc[2][reg] = v2;
    float m = fmaxf(fmaxf(v0, v1), v2);
#pragma unroll
    for (int o = 1; o < 16; o <<= 1) m = fmaxf(m, __shfl_xor(m, o));
    float s = __expf(v0 - m) + __expf(v1 - m) + __expf(v2 - m);
#pragma unroll
    for (int o = 1; o < 16; o <<= 1) s += __shfl_xor(s, o);
    lse[reg] = logf(s) + m;
  }
#pragma unroll
  for (int reg = 0; reg < 4; ++reg) {
    int gr = row0 + quad * 4 + reg;
    if (gr < nrows) {
      out[(size_t)gr * C_CLS + cl] = acc[0][reg] - lse[reg];
      out[(size_t)gr * C_CLS + 16 + cl] = acc[1][reg] - lse[reg];
      if (cl < 8) out[(size_t)gr * C_CLS + 32 + cl] = acc[2][reg] - lse[reg];
    }
  }
}

extern "C" void kernel_launch(void* const* d_in, const int* in_sizes, int n_in,
                              void* d_out, int out_size, void* d_ws, size_t ws_size,
                              hipStream_t stream) {
  const float* x    = (const float*)d_in[0];
  const int*   ei   = (const int*)d_in[1];
  const float* imp  = (const float*)d_in[2];
  const float* W1   = (const float*)d_in[3];
  const float* bl1  = (const float*)d_in[4];
  const float* bc1  = (const float*)d_in[5];
  const float* W2   = (const float*)d_in[6];
  const float* bl2  = (const float*)d_in[7];
  const float* bc2  = (const float*)d_in[8];
  const float* W3   = (const float*)d_in[9];
  const float* bl3  = (const float*)d_in[10];
  const float* bc3  = (const float*)d_in[11];
  const float* Wl1  = (const float*)d_in[12];
  const float* bli1 = (const float*)d_in[13];
  const float* Wl2  = (const float*)d_in[14];
  const float* bli2 = (const float*)d_in[15];
  float* out = (float*)d_out;

  const int N = in_sizes[0] / F;      // 100000
  const int E = in_sizes[1] / 2;      // 600000

  // ping-pong buffers have N+1 rows; row N is the shared zero row for ELL tails
  ushort* A16 = (ushort*)d_ws;                     // (N+1)*F
  ushort* B16 = A16 + (size_t)(N + 1) * F;         // (N+1)*F
  ushort* WhP = B16 + (size_t)(N + 1) * F;         // 8192*8
  ushort* W2hH = WhP + 65536;                      // 768*8
  ushort* W2lH = W2hH + 6144;                      // 768*8
  float* wsum = (float*)(W2lH + 6144);             // N
  int*   cnt  = (int*)(wsum + N);                  // N (packed)
  int*   hist = cnt + N;                           // 9
  int*   cursor = hist + NBKT;                     // 9
  int*   perm = cursor + NBKT;                     // N
  int*   ell  = perm + N;                          // 32N

  const int* rowv = ei;
  const int* colv = ei + E;

  int nbE  = (E + 255) / 256;
  int nbW  = (N + 255) / 256;          // prepass wsum/hist blocks
  int nbX  = (N * F + 2047) / 2048;    // prepass x->Xs blocks (8 elems/thread)
  int nbCv = (N + 63) / 64;            // conv blocks (64 nodes each)
  int nbHd = (N + 63) / 64;

  // ---- one-time prep ----
  hipMemsetAsync(cnt, 0, ((size_t)N + 2 * NBKT) * sizeof(int), stream);
  setup_kernel<<<NWSPLIT + nbE, 256, 0, stream>>>(
      W1, imp, W2, W3, Wl1, Wl2, WhP, W2hH, W2lH, rowv, colv, cnt, ell, E, N);
  prepass_kernel<<<nbW + nbX + 1, 256, 0, stream>>>(
      x, cnt, ell, wsum, hist, B16, A16, N, nbW, nbX);
  perm_kernel<<<nbW, 256, 0, stream>>>(cnt, hist, cursor, perm, N);

  // ---- conv layers: degree-uniform pure-sum gather + fused GEMM ----
  conv_fused<true ><<<nbCv, 256, 0, stream>>>(cnt, ell, perm, B16, WhP,         wsum, bl1, bc1, A16, N);
  conv_fused<true ><<<nbCv, 256, 0, stream>>>(cnt, ell, perm, A16, WhP + 16384, wsum, bl2, bc2, B16, N);
  conv_fused<false><<<nbCv, 256, 0, stream>>>(cnt, ell, perm, B16, WhP + 32768, wsum, bl3, bc3, A16, N);

  // ---- fused dense head + log_softmax ----
  head_fused<<<nbHd, 256, 0, stream>>>(A16, WhP + 49152, bli1, W2hH, W2lH, bli2, out, N);
}